// Round 3
// baseline (81.743 us; speedup 1.0000x reference)
//
#include <hip/hip_runtime.h>
#include <hip/hip_bf16.h>
#include <math.h>

typedef __bf16 bf16x8 __attribute__((ext_vector_type(8)));
typedef float f32x4 __attribute__((ext_vector_type(4)));

namespace {
constexpr int BN   = 8192;   // batch columns
constexpr int DK   = 128;    // feature dim
constexpr int NCAT = 8192;   // cat rows
constexpr int SRC  = 4;      // source chunks
constexpr int RG   = 8;      // row groups (1024 rows each, 2 per chunk)
constexpr int LDK  = 136;    // padded LDS k-stride (bf16)
constexpr int RT   = 256;    // rows staged per LDS tile
constexpr float LOG2E = 1.4426950408889634f;
}

__device__ __forceinline__ float4 ld4(const float* p) {
    return *reinterpret_cast<const float4*>(p);
}

// fp32 -> bf16 (RNE) for both x and cat in one launch
__global__ __launch_bounds__(256) void k_convert2(const float* __restrict__ x,
                                                  const float* __restrict__ cat,
                                                  unsigned short* __restrict__ xb,
                                                  unsigned short* __restrict__ catb) {
    const int i = blockIdx.x * 256 + threadIdx.x;
    const int nx = BN * DK / 8;
    const float* src;
    unsigned short* dst;
    int j;
    if (i < nx) { src = x; dst = xb; j = i; }
    else        { src = cat; dst = catb; j = i - nx; }
    const float4 a = ld4(src + (size_t)j * 8);
    const float4 b = ld4(src + (size_t)j * 8 + 4);
    float vals[8] = {a.x, a.y, a.z, a.w, b.x, b.y, b.z, b.w};
    union { unsigned short u[8]; uint4 v; } o;
#pragma unroll
    for (int q = 0; q < 8; ++q) {
        __hip_bfloat16 h = __float2bfloat16(vals[q]);
        o.u[q] = *reinterpret_cast<unsigned short*>(&h);
    }
    *reinterpret_cast<uint4*>(&dst[(size_t)j * 8]) = o.v;
}

// MFMA pass over a 128-col x 1024-row group. B (x) fragments live in registers
// for the whole kernel; only A (cat) is LDS-staged, 256 rows at a time.
// PASS==1: outA = partial sum(d^4), outB = partial max(d)
// PASS==2: outA = partial Z,        outB = partial sum(y*exp); norms computed in-block
template <int PASS>
__global__ __launch_bounds__(256, 2) void k_pass(
    const unsigned short* __restrict__ xb,    // [BN][DK] bf16
    const unsigned short* __restrict__ catb,  // [NCAT][DK] bf16
    const float* __restrict__ y,
    const float* __restrict__ pp4,            // pass2 input: [RG][BN]
    const float* __restrict__ pmax,           // pass2 input: [RG][BN]
    float* __restrict__ outA,
    float* __restrict__ outB) {
    __shared__ __align__(16) unsigned short As[RT * LDK];  // 69.6 KB
    __shared__ float ysh[RT];
    __shared__ float nsh[128];
    __shared__ float msh[128];
    __shared__ float redA[2][128];
    __shared__ float redB[2][128];

    const int t = threadIdx.x;
    const int colbase = blockIdx.x * 128;
    const int rowgrp = blockIdx.y;            // 0..7
    const int rowbase0 = rowgrp * 1024;

    const int wid = t >> 6;
    const int lane = t & 63;
    const int wr = wid >> 1;                  // row half of 128-row chunk
    const int wc = wid & 1;                   // col half
    const int lr = lane & 15;
    const int kb = lane >> 4;                 // k-block 0..3

    // pass2: reduce pass1 partials for this block's 128 columns -> L, V
    if (PASS == 2 && t < 128) {
        float sp = 0.f, sm = -3.0e38f;
#pragma unroll
        for (int r = 0; r < RG; ++r) {
            sp += pp4[r * BN + colbase + t];
            sm = fmaxf(sm, pmax[r * BN + colbase + t]);
        }
        const float n4 = fmaxf(sqrtf(sqrtf(sp)), 1e-12f);
        const float L = LOG2E / n4;           // exp2 scale
        nsh[t] = L;
        msh[t] = sm * L;
    }

    // hoist B fragments: 16 x bf16x8 (64 VGPR), direct from global (L2-hit)
    bf16x8 Bf[4][4];
#pragma unroll
    for (int j = 0; j < 4; ++j)
#pragma unroll
        for (int kk = 0; kk < 4; ++kk)
            Bf[j][kk] = *reinterpret_cast<const bf16x8*>(
                &xb[(size_t)(colbase + wc * 64 + j * 16 + lr) * DK + kk * 32 + kb * 8]);

    float inm[4], vmx4[4];
    if (PASS == 2) {
        __syncthreads();  // nsh/msh ready
#pragma unroll
        for (int j = 0; j < 4; ++j) {
            inm[j] = nsh[wc * 64 + j * 16 + lr];
            vmx4[j] = msh[wc * 64 + j * 16 + lr];
        }
    }

    float accA[4], accB[4];
#pragma unroll
    for (int j = 0; j < 4; ++j) {
        accA[j] = 0.f;
        accB[j] = (PASS == 1) ? -3.0e38f : 0.f;
    }

    for (int rt0 = 0; rt0 < 1024; rt0 += RT) {
        const int rowbase = rowbase0 + rt0;
        __syncthreads();  // prior reads of As done
#pragma unroll
        for (int q = t; q < RT * 16; q += 256) {
            const int r = q >> 4, kc = q & 15;
            *reinterpret_cast<uint4*>(&As[r * LDK + kc * 8]) =
                *reinterpret_cast<const uint4*>(&catb[(size_t)(rowbase + r) * DK + kc * 8]);
        }
        if (PASS == 2) ysh[t] = y[rowbase + t];
        __syncthreads();

#pragma unroll
        for (int ch = 0; ch < 2; ++ch) {
            f32x4 acc[4][4];
#pragma unroll
            for (int i = 0; i < 4; ++i)
#pragma unroll
                for (int j = 0; j < 4; ++j) acc[i][j] = (f32x4){0.f, 0.f, 0.f, 0.f};

#pragma unroll
            for (int kk = 0; kk < 4; ++kk) {
                bf16x8 a[4];
#pragma unroll
                for (int i = 0; i < 4; ++i)
                    a[i] = *reinterpret_cast<const bf16x8*>(
                        &As[(ch * 128 + wr * 64 + i * 16 + lr) * LDK + kk * 32 + kb * 8]);
#pragma unroll
                for (int i = 0; i < 4; ++i)
#pragma unroll
                    for (int j = 0; j < 4; ++j)
                        acc[i][j] = __builtin_amdgcn_mfma_f32_16x16x32_bf16(
                            a[i], Bf[j][kk], acc[i][j], 0, 0, 0);
            }

            if (PASS == 1) {
#pragma unroll
                for (int i = 0; i < 4; ++i)
#pragma unroll
                    for (int j = 0; j < 4; ++j)
#pragma unroll
                        for (int r = 0; r < 4; ++r) {
                            const float v = acc[i][j][r];
                            const float v2 = v * v;
                            accA[j] = fmaf(v2, v2, accA[j]);
                            accB[j] = fmaxf(accB[j], v);
                        }
            } else {
#pragma unroll
                for (int i = 0; i < 4; ++i)
#pragma unroll
                    for (int r = 0; r < 4; ++r) {
                        const float yr = ysh[ch * 128 + wr * 64 + i * 16 + kb * 4 + r];
#pragma unroll
                        for (int j = 0; j < 4; ++j) {
                            const float e = exp2f(fmaf(acc[i][j][r], inm[j], -vmx4[j]));
                            accA[j] += e;
                            accB[j] = fmaf(yr, e, accB[j]);
                        }
                    }
            }
        }
    }

    // reduce over k-block groups (lane bits 4-5)
#pragma unroll
    for (int j = 0; j < 4; ++j) {
        float a16 = __shfl_xor(accA[j], 16, 64);
        float b16 = __shfl_xor(accB[j], 16, 64);
        accA[j] += a16;
        accB[j] = (PASS == 1) ? fmaxf(accB[j], b16) : accB[j] + b16;
        float a32 = __shfl_xor(accA[j], 32, 64);
        float b32 = __shfl_xor(accB[j], 32, 64);
        accA[j] += a32;
        accB[j] = (PASS == 1) ? fmaxf(accB[j], b32) : accB[j] + b32;
    }

    if (lane < 16) {
#pragma unroll
        for (int j = 0; j < 4; ++j) {
            redA[wr][wc * 64 + j * 16 + lane] = accA[j];
            redB[wr][wc * 64 + j * 16 + lane] = accB[j];
        }
    }
    __syncthreads();
    if (t < 128) {
        const float a = redA[0][t] + redA[1][t];
        const float b = (PASS == 1) ? fmaxf(redB[0][t], redB[1][t])
                                    : redB[0][t] + redB[1][t];
        outA[(size_t)rowgrp * BN + colbase + t] = a;
        outB[(size_t)rowgrp * BN + colbase + t] = b;
    }
}

// Final: 4 threads per output (one per source), xor-reduce
__global__ __launch_bounds__(256) void k_final(const float* __restrict__ x,
                                               const float* __restrict__ phi,
                                               const float* __restrict__ pZ,
                                               const float* __restrict__ pW,
                                               const float* __restrict__ bias,
                                               float* __restrict__ out) {
    const int g = blockIdx.x * 256 + threadIdx.x;
    const int b = g >> 2, s = g & 3;
    float dot = 0.f;
#pragma unroll
    for (int k = 0; k < DK; k += 4) {
        const float4 xv = ld4(&x[(size_t)b * DK + k]);
        const float4 pv = ld4(&phi[s * DK + k]);
        dot += xv.x * pv.x + xv.y * pv.y + xv.z * pv.z + xv.w * pv.w;
    }
    const float W = pW[(size_t)(2 * s) * BN + b] + pW[(size_t)(2 * s + 1) * BN + b];
    float v = __expf(dot) * W;
    float Z = pZ[(size_t)(2 * s) * BN + b] + pZ[(size_t)(2 * s + 1) * BN + b];
    v += __shfl_xor(v, 1, 64);
    v += __shfl_xor(v, 2, 64);
    Z += __shfl_xor(Z, 1, 64);
    Z += __shfl_xor(Z, 2, 64);
    if (s == 0) out[b] = v / Z + bias[0];
}

extern "C" void kernel_launch(void* const* d_in, const int* in_sizes, int n_in,
                              void* d_out, int out_size, void* d_ws, size_t ws_size,
                              hipStream_t stream) {
    const float* x    = (const float*)d_in[0];
    const float* cat  = (const float*)d_in[1];
    const float* y    = (const float*)d_in[2];
    const float* phi  = (const float*)d_in[3];
    const float* bias = (const float*)d_in[4];
    float* out = (float*)d_out;

    char* ws = (char*)d_ws;
    unsigned short* xb   = (unsigned short*)ws;            // BN*DK bf16 (2MB)
    unsigned short* catb = xb + (size_t)BN * DK;           // 2MB
    float* pp4 = (float*)(catb + (size_t)NCAT * DK);       // RG*BN
    float* pmax = pp4 + (size_t)RG * BN;                   // RG*BN
    float* pZ = pmax + (size_t)RG * BN;                    // RG*BN
    float* pW = pZ + (size_t)RG * BN;                      // RG*BN

    k_convert2<<<(BN * DK + NCAT * DK) / 8 / 256, 256, 0, stream>>>(x, cat, xb, catb);
    k_pass<1><<<dim3(BN / 128, RG), 256, 0, stream>>>(xb, catb, y, nullptr, nullptr,
                                                      pp4, pmax);
    k_pass<2><<<dim3(BN / 128, RG), 256, 0, stream>>>(xb, catb, y, pp4, pmax, pZ, pW);
    k_final<<<BN * SRC / 256, 256, 0, stream>>>(x, phi, pZ, pW, bias, out);
}

// Round 4
// 64.135 us; speedup vs baseline: 1.2745x; 1.2745x over previous
//
#include <hip/hip_runtime.h>
#include <hip/hip_bf16.h>
#include <math.h>

typedef __bf16 bf16x8 __attribute__((ext_vector_type(8)));
typedef float f32x4 __attribute__((ext_vector_type(4)));

namespace {
constexpr int BN   = 8192;   // batch columns
constexpr int DK   = 128;    // feature dim
constexpr int NCAT = 8192;   // cat rows
constexpr int SRC  = 4;      // source chunks
constexpr int RG   = 8;      // row groups (1024 rows each)
constexpr int TROWS = 128;   // rows per LDS tile
constexpr int NT   = 8;      // tiles per rowgroup
constexpr float LOG2E = 1.4426950408889634f;
}

__device__ __forceinline__ float4 ld4(const float* p) {
    return *reinterpret_cast<const float4*>(p);
}

// fp32 -> bf16 (RNE) for both x and cat in one launch
__global__ __launch_bounds__(256) void k_convert2(const float* __restrict__ x,
                                                  const float* __restrict__ cat,
                                                  unsigned short* __restrict__ xb,
                                                  unsigned short* __restrict__ catb) {
    const int i = blockIdx.x * 256 + threadIdx.x;
    const int nx = BN * DK / 8;
    const float* src;
    unsigned short* dst;
    int j;
    if (i < nx) { src = x; dst = xb; j = i; }
    else        { src = cat; dst = catb; j = i - nx; }
    const float4 a = ld4(src + (size_t)j * 8);
    const float4 b = ld4(src + (size_t)j * 8 + 4);
    float vals[8] = {a.x, a.y, a.z, a.w, b.x, b.y, b.z, b.w};
    union { unsigned short u[8]; uint4 v; } o;
#pragma unroll
    for (int q = 0; q < 8; ++q) {
        __hip_bfloat16 h = __float2bfloat16(vals[q]);
        o.u[q] = *reinterpret_cast<unsigned short*>(&h);
    }
    *reinterpret_cast<uint4*>(&dst[(size_t)j * 8]) = o.v;
}

// MFMA pass over 128 cols x 1024 rows. B (x) fragments in registers all kernel;
// A (cat) double-buffered in LDS, XOR-swizzled, 2-phase pipelined:
//   issue loads(t+1) -> compute(t) -> ds_write(t+1) -> barrier.
// No softmax max needed: |d|/norm4 <= 1 provably (norm4 >= max|d|).
// PASS==1: outA = partial sum(d^4)
// PASS==2: outA = partial Z, outB = partial sum(y*exp); norms from pp4in in-block
template <int PASS>
__global__ __launch_bounds__(256, 2) void k_pass(
    const unsigned short* __restrict__ xb,    // [BN][DK] bf16
    const unsigned short* __restrict__ catb,  // [NCAT][DK] bf16
    const float* __restrict__ y,
    const float* __restrict__ pp4in,          // pass2: [RG][BN]
    float* __restrict__ outA,
    float* __restrict__ outB) {
    __shared__ __align__(16) unsigned short As[2][TROWS * DK];  // 64 KB
    __shared__ float ysh[2][TROWS];
    __shared__ float nsh[128];
    __shared__ float redA[2][128];
    __shared__ float redB[2][128];

    const int t = threadIdx.x;
    const int colbase = blockIdx.x * 128;
    const int rowgrp = blockIdx.y;            // 0..7
    const int rowbase0 = rowgrp * 1024;

    const int wid = t >> 6;
    const int lane = t & 63;
    const int wr = wid >> 1;                  // row half
    const int wc = wid & 1;                   // col half
    const int lr = lane & 15;
    const int kb = lane >> 4;                 // k-block 0..3

    // staging geometry: thread t stages 8 chunks of 16B; chunk c=q*256+t
    // row r = c>>4, col-slot c16 = t&15; LDS slot XOR-swizzled by (r&7)
    const int srow = t >> 4;                  // 0..15
    const int scol = t & 15;

    // issue tile-0 global loads (latency covered by Bf loads + norm reduce)
    uint4 stg[8];
    {
        const unsigned short* tb = catb + (size_t)rowbase0 * DK;
#pragma unroll
        for (int q = 0; q < 8; ++q)
            stg[q] = *reinterpret_cast<const uint4*>(tb + (size_t)(q * 256 + t) * 8);
    }

    // B fragments: 16 x bf16x8 (64 VGPR), from global (L2-hit), once
    bf16x8 Bf[4][4];
#pragma unroll
    for (int j = 0; j < 4; ++j)
#pragma unroll
        for (int kk = 0; kk < 4; ++kk)
            Bf[j][kk] = *reinterpret_cast<const bf16x8*>(
                &xb[(size_t)(colbase + wc * 64 + j * 16 + lr) * DK + kk * 32 + kb * 8]);

    if (PASS == 2) {
        if (t < 128) {
            float sp = 0.f;
#pragma unroll
            for (int r = 0; r < RG; ++r) sp += pp4in[r * BN + colbase + t];
            nsh[t] = LOG2E / fmaxf(sqrtf(sqrtf(sp)), 1e-12f);
        }
        if (t < TROWS) ysh[0][t] = y[rowbase0 + t];
    }

    // write tile 0 (swizzled)
#pragma unroll
    for (int q = 0; q < 8; ++q) {
        const int r = q * 16 + srow;
        *reinterpret_cast<uint4*>(&As[0][r * DK + (scol ^ (r & 7)) * 8]) = stg[q];
    }
    __syncthreads();

    float inm[4];
    if (PASS == 2) {
#pragma unroll
        for (int j = 0; j < 4; ++j) inm[j] = nsh[wc * 64 + j * 16 + lr];
    }

    float accA[4] = {0.f, 0.f, 0.f, 0.f};
    float accB[4] = {0.f, 0.f, 0.f, 0.f};

    for (int tl = 0; tl < NT; ++tl) {
        const int cur = tl & 1, nxt = cur ^ 1;
        float yreg = 0.f;
        if (tl < NT - 1) {  // issue next-tile loads (land during compute)
            const unsigned short* nb =
                catb + (size_t)(rowbase0 + (tl + 1) * TROWS) * DK;
#pragma unroll
            for (int q = 0; q < 8; ++q)
                stg[q] = *reinterpret_cast<const uint4*>(nb + (size_t)(q * 256 + t) * 8);
            if (PASS == 2 && t < TROWS) yreg = y[rowbase0 + (tl + 1) * TROWS + t];
        }

        // compute current tile
        f32x4 acc[4][4];
#pragma unroll
        for (int i = 0; i < 4; ++i)
#pragma unroll
            for (int j = 0; j < 4; ++j) acc[i][j] = (f32x4){0.f, 0.f, 0.f, 0.f};

#pragma unroll
        for (int kk = 0; kk < 4; ++kk) {
            bf16x8 a[4];
#pragma unroll
            for (int i = 0; i < 4; ++i) {
                const int row = wr * 64 + i * 16 + lr;
                a[i] = *reinterpret_cast<const bf16x8*>(
                    &As[cur][row * DK + ((kk * 32 + kb * 8) ^ ((lr & 7) * 8))]);
            }
#pragma unroll
            for (int i = 0; i < 4; ++i)
#pragma unroll
                for (int j = 0; j < 4; ++j)
                    acc[i][j] = __builtin_amdgcn_mfma_f32_16x16x32_bf16(
                        a[i], Bf[j][kk], acc[i][j], 0, 0, 0);
        }

        if (PASS == 1) {
#pragma unroll
            for (int i = 0; i < 4; ++i)
#pragma unroll
                for (int j = 0; j < 4; ++j)
#pragma unroll
                    for (int r = 0; r < 4; ++r) {
                        const float v = acc[i][j][r];
                        const float v2 = v * v;
                        accA[j] = fmaf(v2, v2, accA[j]);
                    }
        } else {
#pragma unroll
            for (int i = 0; i < 4; ++i)
#pragma unroll
                for (int r = 0; r < 4; ++r) {
                    const float yr = ysh[cur][wr * 64 + i * 16 + kb * 4 + r];
#pragma unroll
                    for (int j = 0; j < 4; ++j) {
                        const float e = exp2f(acc[i][j][r] * inm[j]);
                        accA[j] += e;
                        accB[j] = fmaf(yr, e, accB[j]);
                    }
                }
        }

        // write next tile into other buffer (loads have landed by now)
        if (tl < NT - 1) {
#pragma unroll
            for (int q = 0; q < 8; ++q) {
                const int r = q * 16 + srow;
                *reinterpret_cast<uint4*>(&As[nxt][r * DK + (scol ^ (r & 7)) * 8]) = stg[q];
            }
            if (PASS == 2 && t < TROWS) ysh[nxt][t] = yreg;
        }
        __syncthreads();
    }

    // reduce over k-block groups (lane bits 4-5)
#pragma unroll
    for (int j = 0; j < 4; ++j) {
        accA[j] += __shfl_xor(accA[j], 16, 64);
        accA[j] += __shfl_xor(accA[j], 32, 64);
        if (PASS == 2) {
            accB[j] += __shfl_xor(accB[j], 16, 64);
            accB[j] += __shfl_xor(accB[j], 32, 64);
        }
    }
    if (lane < 16) {
#pragma unroll
        for (int j = 0; j < 4; ++j) {
            redA[wr][wc * 64 + j * 16 + lane] = accA[j];
            if (PASS == 2) redB[wr][wc * 64 + j * 16 + lane] = accB[j];
        }
    }
    __syncthreads();
    if (t < 128) {
        outA[(size_t)rowgrp * BN + colbase + t] = redA[0][t] + redA[1][t];
        if (PASS == 2)
            outB[(size_t)rowgrp * BN + colbase + t] = redB[0][t] + redB[1][t];
    }
}

// Final: 4 threads per output (one per source), xor-reduce
__global__ __launch_bounds__(256) void k_final(const float* __restrict__ x,
                                               const float* __restrict__ phi,
                                               const float* __restrict__ pZ,
                                               const float* __restrict__ pW,
                                               const float* __restrict__ bias,
                                               float* __restrict__ out) {
    const int g = blockIdx.x * 256 + threadIdx.x;
    const int b = g >> 2, s = g & 3;
    float dot = 0.f;
#pragma unroll
    for (int k = 0; k < DK; k += 4) {
        const float4 xv = ld4(&x[(size_t)b * DK + k]);
        const float4 pv = ld4(&phi[s * DK + k]);
        dot += xv.x * pv.x + xv.y * pv.y + xv.z * pv.z + xv.w * pv.w;
    }
    const float W = pW[(size_t)(2 * s) * BN + b] + pW[(size_t)(2 * s + 1) * BN + b];
    float v = __expf(dot) * W;
    float Z = pZ[(size_t)(2 * s) * BN + b] + pZ[(size_t)(2 * s + 1) * BN + b];
    v += __shfl_xor(v, 1, 64);
    v += __shfl_xor(v, 2, 64);
    Z += __shfl_xor(Z, 1, 64);
    Z += __shfl_xor(Z, 2, 64);
    if (s == 0) out[b] = v / Z + bias[0];
}

extern "C" void kernel_launch(void* const* d_in, const int* in_sizes, int n_in,
                              void* d_out, int out_size, void* d_ws, size_t ws_size,
                              hipStream_t stream) {
    const float* x    = (const float*)d_in[0];
    const float* cat  = (const float*)d_in[1];
    const float* y    = (const float*)d_in[2];
    const float* phi  = (const float*)d_in[3];
    const float* bias = (const float*)d_in[4];
    float* out = (float*)d_out;

    char* ws = (char*)d_ws;
    unsigned short* xb   = (unsigned short*)ws;            // BN*DK bf16 (2MB)
    unsigned short* catb = xb + (size_t)BN * DK;           // 2MB
    float* pp4 = (float*)(catb + (size_t)NCAT * DK);       // RG*BN
    float* pZ  = pp4 + (size_t)RG * BN;                    // RG*BN
    float* pW  = pZ + (size_t)RG * BN;                     // RG*BN

    k_convert2<<<(BN * DK + NCAT * DK) / 8 / 256, 256, 0, stream>>>(x, cat, xb, catb);
    k_pass<1><<<dim3(BN / 128, RG), 256, 0, stream>>>(xb, catb, y, nullptr, pp4, nullptr);
    k_pass<2><<<dim3(BN / 128, RG), 256, 0, stream>>>(xb, catb, y, pp4, pZ, pW);
    k_final<<<BN * SRC / 256, 256, 0, stream>>>(x, phi, pZ, pW, bias, out);
}